// Round 3
// baseline (48.766 us; speedup 1.0000x reference)
//
#include <hip/hip_runtime.h>

// gated pool: x (32,128,112,112) f32, mask (1,1,2,2) f32, K=S=2 VALID
// out (32,128,56,56) f32
// per output pixel: gate = sum(win*mask); a = sigmoid(gate);
// out = a*max(win) + (1-a)*avg(win)
//
// One thread = 4 adjacent output pixels (one 16B store):
//   reads 2x 16B from each of the two input rows (64 B/lane),
//   writes 1x 16B. All streams nontemporal (zero reuse,
//   input+output > 256MB L3).

#define BC    4096   // 32*128
#define H_IN  112
#define W_IN  112
#define H_OUT 56
#define W_OUT 56
#define WOQ   14     // W_OUT/4: output quads per row

typedef float vf4 __attribute__((ext_vector_type(4)));

__global__ __launch_bounds__(256) void gated_pool_kernel(
    const float* __restrict__ x,
    const float* __restrict__ mask,
    float* __restrict__ out)
{
    const float m00 = mask[0];
    const float m01 = mask[1];
    const float m10 = mask[2];
    const float m11 = mask[3];

    const int p = blockIdx.x * 256 + threadIdx.x;  // exactly npq threads

    // p -> (bc, ho, wq)
    const int wq = p % WOQ;
    const int t  = p / WOQ;
    const int ho = t % H_OUT;
    const int bc = t / H_OUT;

    const size_t in_base = (size_t)bc * (H_IN * W_IN) + (size_t)(2 * ho) * W_IN + 8 * wq;
    const vf4* p00 = reinterpret_cast<const vf4*>(x + in_base);
    const vf4* p10 = reinterpret_cast<const vf4*>(x + in_base + W_IN);

    const vf4 r0a = __builtin_nontemporal_load(p00);
    const vf4 r0b = __builtin_nontemporal_load(p00 + 1);
    const vf4 r1a = __builtin_nontemporal_load(p10);
    const vf4 r1b = __builtin_nontemporal_load(p10 + 1);

    vf4 o;

    {
        float a = r0a.x, b = r0a.y, c = r1a.x, d = r1a.y;
        float gate  = m00 * a + m01 * b + m10 * c + m11 * d;
        float alpha = 1.0f / (1.0f + __expf(-gate));
        float mx    = fmaxf(fmaxf(a, b), fmaxf(c, d));
        float av    = (a + b + c + d) * 0.25f;
        o.x = alpha * mx + (1.0f - alpha) * av;
    }
    {
        float a = r0a.z, b = r0a.w, c = r1a.z, d = r1a.w;
        float gate  = m00 * a + m01 * b + m10 * c + m11 * d;
        float alpha = 1.0f / (1.0f + __expf(-gate));
        float mx    = fmaxf(fmaxf(a, b), fmaxf(c, d));
        float av    = (a + b + c + d) * 0.25f;
        o.y = alpha * mx + (1.0f - alpha) * av;
    }
    {
        float a = r0b.x, b = r0b.y, c = r1b.x, d = r1b.y;
        float gate  = m00 * a + m01 * b + m10 * c + m11 * d;
        float alpha = 1.0f / (1.0f + __expf(-gate));
        float mx    = fmaxf(fmaxf(a, b), fmaxf(c, d));
        float av    = (a + b + c + d) * 0.25f;
        o.z = alpha * mx + (1.0f - alpha) * av;
    }
    {
        float a = r0b.z, b = r0b.w, c = r1b.z, d = r1b.w;
        float gate  = m00 * a + m01 * b + m10 * c + m11 * d;
        float alpha = 1.0f / (1.0f + __expf(-gate));
        float mx    = fmaxf(fmaxf(a, b), fmaxf(c, d));
        float av    = (a + b + c + d) * 0.25f;
        o.w = alpha * mx + (1.0f - alpha) * av;
    }

    const size_t out_base = (size_t)bc * (H_OUT * W_OUT) + (size_t)ho * W_OUT + 4 * wq;
    __builtin_nontemporal_store(o, reinterpret_cast<vf4*>(out + out_base));
}

extern "C" void kernel_launch(void* const* d_in, const int* in_sizes, int n_in,
                              void* d_out, int out_size, void* d_ws, size_t ws_size,
                              hipStream_t stream) {
    const float* x    = (const float*)d_in[0];
    const float* mask = (const float*)d_in[1];
    float* out        = (float*)d_out;

    const int npq  = BC * H_OUT * WOQ;   // 3,211,264 = 12544 * 256
    const int grid = npq / 256;          // 12544 blocks, 1 quad/thread

    gated_pool_kernel<<<grid, 256, 0, stream>>>(x, mask, out);
}

// Round 4
// 40.701 us; speedup vs baseline: 1.1981x; 1.1981x over previous
//
#include <hip/hip_runtime.h>

// gated pool: x (32,128,112,112) f32, mask (1,1,2,2) f32, K=S=2 VALID
// out (32,128,56,56) f32
// per output pixel: gate = sum(win*mask); a = sigmoid(gate);
// out = a*max(win) + (1-a)*avg(win)
//
// Round-1 memory shape (best so far, 42.7us):
//   one thread = 2 adjacent output pixels; reads one fully-coalesced
//   float4 from each of the two input rows (16B/lane/inst), writes one
//   float2. Changes vs round 1: exact grid (no grid-stride loop) and
//   nontemporal STORE only (output is write-once, never re-read).

#define BC    4096   // 32*128
#define H_IN  112
#define W_IN  112
#define H_OUT 56
#define W_OUT 56
#define WOP   28     // W_OUT/2: output-pixel pairs per row

typedef float vf4 __attribute__((ext_vector_type(4)));
typedef float vf2 __attribute__((ext_vector_type(2)));

__global__ __launch_bounds__(256) void gated_pool_kernel(
    const float* __restrict__ x,
    const float* __restrict__ mask,
    float* __restrict__ out)
{
    const float m00 = mask[0];
    const float m01 = mask[1];
    const float m10 = mask[2];
    const float m11 = mask[3];

    const int p = blockIdx.x * 256 + threadIdx.x;  // exactly npairs threads

    // p -> (bc, ho, wop)
    const int wop = p % WOP;
    const int t   = p / WOP;
    const int ho  = t % H_OUT;
    const int bc  = t / H_OUT;

    const size_t in_base = (size_t)bc * (H_IN * W_IN) + (size_t)(2 * ho) * W_IN + 4 * wop;
    const vf4 r0 = *reinterpret_cast<const vf4*>(x + in_base);
    const vf4 r1 = *reinterpret_cast<const vf4*>(x + in_base + W_IN);

    vf2 o;
    {
        float a = r0.x, b = r0.y, c = r1.x, d = r1.y;
        float gate  = m00 * a + m01 * b + m10 * c + m11 * d;
        float alpha = 1.0f / (1.0f + __expf(-gate));
        float mx    = fmaxf(fmaxf(a, b), fmaxf(c, d));
        float av    = (a + b + c + d) * 0.25f;
        o.x = alpha * mx + (1.0f - alpha) * av;
    }
    {
        float a = r0.z, b = r0.w, c = r1.z, d = r1.w;
        float gate  = m00 * a + m01 * b + m10 * c + m11 * d;
        float alpha = 1.0f / (1.0f + __expf(-gate));
        float mx    = fmaxf(fmaxf(a, b), fmaxf(c, d));
        float av    = (a + b + c + d) * 0.25f;
        o.y = alpha * mx + (1.0f - alpha) * av;
    }

    const size_t out_base = (size_t)bc * (H_OUT * W_OUT) + (size_t)ho * W_OUT + 2 * wop;
    __builtin_nontemporal_store(o, reinterpret_cast<vf2*>(out + out_base));
}

extern "C" void kernel_launch(void* const* d_in, const int* in_sizes, int n_in,
                              void* d_out, int out_size, void* d_ws, size_t ws_size,
                              hipStream_t stream) {
    const float* x    = (const float*)d_in[0];
    const float* mask = (const float*)d_in[1];
    float* out        = (float*)d_out;

    const int npairs = BC * H_OUT * WOP;   // 6,422,528 = 25088 * 256
    const int grid   = npairs / 256;       // 25088 blocks, 1 pair/thread

    gated_pool_kernel<<<grid, 256, 0, stream>>>(x, mask, out);
}